// Round 16
// baseline (416.560 us; speedup 1.0000x reference)
//
#include <hip/hip_runtime.h>
#include <hip/hip_fp16.h>

#define N_NODES 65536
#define N_EDGES 1048576
#define N_LABEL 2097152
#define DIM_IN 32
#define DIM_H 64

typedef short short8 __attribute__((ext_vector_type(8)));
typedef float floatx4 __attribute__((ext_vector_type(4)));

// ---------------- CSR build + norm precompute ----------------
// packed[v]: high 32 = edge count, low 32 = sum(w) in 2^-24 fixed point.
// ONE 64-bit atomic per edge; return value = edge's rank among same-dst edges.
// Features are stored PRE-SCALED (h' = dinv * h), so CSR entries need only
// {src, w} -> k_fill does no random dinv gathers.

__global__ void k_init(unsigned long long* __restrict__ packed) {
    int v = blockIdx.x * blockDim.x + threadIdx.x;
    packed[v] = 0ull;
}

__global__ void k_cnt(const int* __restrict__ ei, const float* __restrict__ w,
                      unsigned long long* __restrict__ packed,
                      unsigned short* __restrict__ rank) {
    int e = blockIdx.x * blockDim.x + threadIdx.x;
    int d = ei[N_EDGES + e];
    unsigned fx = __float2uint_rn(w[e] * 16777216.f);   // w in [0,1)
    unsigned long long old = atomicAdd(&packed[d], (1ull << 32) | (unsigned long long)fx);
    rank[e] = (unsigned short)(old >> 32);
}

// hierarchical exclusive scan over counts (high words) (64 blocks x 1024)
__global__ void k_scan1(const int2* __restrict__ packed, int* __restrict__ blksum) {
    int tid = threadIdx.x;
    const int2* p = packed + blockIdx.x * 1024 + tid * 4;
    int s = p[0].y + p[1].y + p[2].y + p[3].y;
    for (int d = 1; d < 64; d <<= 1) s += __shfl_xor(s, d);
    __shared__ int wsum[4];
    if ((tid & 63) == 0) wsum[tid >> 6] = s;
    __syncthreads();
    if (tid == 0) blksum[blockIdx.x] = wsum[0] + wsum[1] + wsum[2] + wsum[3];
}

__global__ void k_scan2(int* __restrict__ blksum) {
    if (threadIdx.x == 0) {
        int run = 0;
        for (int i = 0; i < 64; ++i) { int t = blksum[i]; blksum[i] = run; run += t; }
    }
}

// scan3 also produces dinv (merged k_dinv)
__global__ void k_scan3(const int2* __restrict__ packed, const int* __restrict__ blksum,
                        int* __restrict__ offs, float* __restrict__ dinv) {
    int tid = threadIdx.x, bid = blockIdx.x;
    const int2* p = packed + bid * 1024 + tid * 4;
    int2 e0 = p[0], e1 = p[1], e2 = p[2], e3 = p[3];
    int c0 = e0.y, c1 = e1.y, c2 = e2.y, c3 = e3.y;
    int s = c0 + c1 + c2 + c3;
    int lane = tid & 63, wid = tid >> 6;
    int sc = s;
    for (int d = 1; d < 64; d <<= 1) {
        int t = __shfl_up(sc, d);
        if (lane >= d) sc += t;
    }
    __shared__ int wsum[4];
    if (lane == 63) wsum[wid] = sc;
    __syncthreads();
    int base = blksum[bid];
    for (int w2 = 0; w2 < wid; ++w2) base += wsum[w2];
    int ex = base + sc - s;  // exclusive prefix of this thread's 4 entries
    int idx = bid * 1024 + tid * 4;
    int o0 = ex, o1 = o0 + c0, o2 = o1 + c1, o3 = o2 + c2;
    offs[idx] = o0; offs[idx + 1] = o1; offs[idx + 2] = o2; offs[idx + 3] = o3;
    if (bid == 63 && tid == 255) offs[N_NODES] = o3 + c3;  // == N_EDGES
    const float FXI = 1.f / 16777216.f;
    dinv[idx]     = rsqrtf(1.f + (float)(unsigned)e0.x * FXI);
    dinv[idx + 1] = rsqrtf(1.f + (float)(unsigned)e1.x * FXI);
    dinv[idx + 2] = rsqrtf(1.f + (float)(unsigned)e2.x * FXI);
    dinv[idx + 3] = rsqrtf(1.f + (float)(unsigned)e3.x * FXI);
}

// packed CSR entry: {src, w-as-bits}; position from offs + rank; NO random gathers
__global__ void k_fill(const int* __restrict__ ei, const float* __restrict__ w,
                       const int* __restrict__ offs, const unsigned short* __restrict__ rank,
                       int2* __restrict__ csr_se) {
    int e = blockIdx.x * blockDim.x + threadIdx.x;
    int s = ei[e];
    int d = ei[N_EDGES + e];
    int pos = offs[d] + rank[e];
    csr_se[pos] = make_int2(s, __float_as_int(w[e]));
}

// ---------------- cast x to PRE-SCALED fp16: xh = dinv * x ----------------

__global__ void k_cast_x(const float* __restrict__ x, const float* __restrict__ dinv,
                         __half* __restrict__ xh) {
    int gid = blockIdx.x * 256 + threadIdx.x;  // N*32 threads
    int v = gid >> 5;
    xh[gid] = __float2half(x[gid] * dinv[v]);
}

// ---------------- aggregation: agg[v] = dinv[v] * ( h'[v] + sum_e w_e h'[src] ) ----------------

template <int K>
__global__ void __launch_bounds__(256) k_agg(
        const int* __restrict__ offs, const int2* __restrict__ csr_se,
        const __half* __restrict__ h, const float* __restrict__ dinv,
        float* __restrict__ agg) {
    constexpr int LPE = K / 8;     // lanes per edge row (uint4 each): 4 or 8
    constexpr int EPI = 64 / LPE;  // edges per gather instruction: 16 or 8

    int tid = threadIdx.x;
    int v = blockIdx.x * 4 + (tid >> 6);
    int lane = tid & 63;
    int sub = lane % LPE;          // 16 B chunk of row
    int g   = lane / LPE;          // edge slot

    float a[8] = {0.f, 0.f, 0.f, 0.f, 0.f, 0.f, 0.f, 0.f};

    // self-loop term: + h'[v] (weight 1; overall dinv[v] applied at the end)
    if (g == 0) {
        uint4 rv = *(const uint4*)(h + (size_t)v * K + sub * 8);
        const __half2* hp = (const __half2*)&rv;
#pragma unroll
        for (int i = 0; i < 4; ++i) {
            float2 f = __half22float2(hp[i]);
            a[2 * i]     += f.x;
            a[2 * i + 1] += f.y;
        }
    }

    int j0 = __builtin_amdgcn_readfirstlane(offs[v]);
    int j1 = __builtin_amdgcn_readfirstlane(offs[v + 1]);

    for (int jm = j0; jm < j1; jm += 64) {
        int mi = jm + lane;
        int2 md = csr_se[mi < j1 ? mi : j1 - 1];   // loop entered => j1 > j0
        if (mi >= j1) md.y = 0;                    // 0.0f weight for padding slots
        int nwin = j1 - jm;
        if (nwin > 64) nwin = 64;
        for (int t = 0; t * EPI < nwin; ++t) {     // wave-uniform trip count
            int we = t * EPI + g;                  // window slot (< 64)
            int src = __shfl(md.x, we);            // all 64 lanes active
            float wv = __int_as_float(__shfl(md.y, we));
            uint4 rv = *(const uint4*)(h + (size_t)src * K + sub * 8);
            const __half2* hp = (const __half2*)&rv;
#pragma unroll
            for (int i = 0; i < 4; ++i) {
                float2 f = __half22float2(hp[i]);
                a[2 * i]     += wv * f.x;
                a[2 * i + 1] += wv * f.y;
            }
        }
    }

    // xor-tree: sum partials across edge slots
#pragma unroll
    for (int st = LPE; st < 64; st <<= 1) {
#pragma unroll
        for (int i = 0; i < 8; ++i) a[i] += __shfl_xor(a[i], st);
    }

    // final dinv[v] scale; lanes 0..LPE-1 write their 8-float chunk, coalesced
    if (lane < LPE) {
        float dv = dinv[v];
        float* dst = agg + (size_t)v * K + lane * 8;
        *(float4*)(dst)     = make_float4(dv * a[0], dv * a[1], dv * a[2], dv * a[3]);
        *(float4*)(dst + 4) = make_float4(dv * a[4], dv * a[5], dv * a[6], dv * a[7]);
    }
}

// ---------------- dense transform via MFMA: out = [dinv*] relu(agg @ W + b) ----------------
// bf16 hi/lo split: hi@Whi + hi@Wlo + lo@Whi (drop lo@Wlo) -> fp32-accurate.
// SCALE=true (layers 1-5): writes PRE-SCALED h' = dinv * relu(...). Layer 6: raw enc.

__device__ __forceinline__ unsigned short f32_bf16(float f) {
    unsigned u = __float_as_uint(f);
    unsigned r = u + 0x7FFFu + ((u >> 16) & 1u);
    return (unsigned short)(r >> 16);
}
__device__ __forceinline__ float bf16_f32(unsigned short h) {
    return __uint_as_float(((unsigned)h) << 16);
}

template <int KIN, bool RELU, bool SCALE>
__global__ void __launch_bounds__(256) k_gemm_mfma(
        const float* __restrict__ agg, const float* __restrict__ W,
        const float* __restrict__ b, const float* __restrict__ dinv,
        __half* __restrict__ out) {
    constexpr int KC = KIN / 32;           // k-chunks of 32
    constexpr int NT = N_NODES / 16;       // 16-row tiles
    __shared__ float Wl[KIN * 64];
    int tid = threadIdx.x;
    for (int i = tid; i < KIN * 64; i += 256) Wl[i] = W[i];
    __syncthreads();

    int lane = tid & 63;
    int l15 = lane & 15, l4 = lane >> 4;

    // B fragments (W), hi/lo, built once per wave
    short8 whi[4][KC], wlo[4][KC];
#pragma unroll
    for (int ct = 0; ct < 4; ++ct)
#pragma unroll
        for (int kc = 0; kc < KC; ++kc)
#pragma unroll
            for (int j = 0; j < 8; ++j) {
                float wv = Wl[(kc * 32 + l4 * 8 + j) * 64 + ct * 16 + l15];
                unsigned short hi = f32_bf16(wv);
                unsigned short lo = f32_bf16(wv - bf16_f32(hi));
                whi[ct][kc][j] = (short)hi;
                wlo[ct][kc][j] = (short)lo;
            }
    float bias[4];
#pragma unroll
    for (int ct = 0; ct < 4; ++ct) bias[ct] = b[ct * 16 + l15];

    int wave_id = blockIdx.x * 4 + (tid >> 6);          // 2048 waves
    for (int tile = wave_id; tile < NT; tile += 2048) {
        int r0 = tile * 16;
        const float* arow = agg + (size_t)(r0 + l15) * KIN + l4 * 8;
        short8 ahi[KC], alo[KC];
#pragma unroll
        for (int kc = 0; kc < KC; ++kc) {
            float4 f0 = *(const float4*)(arow + kc * 32);
            float4 f1 = *(const float4*)(arow + kc * 32 + 4);
            float fv[8] = {f0.x, f0.y, f0.z, f0.w, f1.x, f1.y, f1.z, f1.w};
#pragma unroll
            for (int j = 0; j < 8; ++j) {
                unsigned short hi = f32_bf16(fv[j]);
                unsigned short lo = f32_bf16(fv[j] - bf16_f32(hi));
                ahi[kc][j] = (short)hi;
                alo[kc][j] = (short)lo;
            }
        }
        floatx4 acc[4] = {{0.f,0.f,0.f,0.f},{0.f,0.f,0.f,0.f},{0.f,0.f,0.f,0.f},{0.f,0.f,0.f,0.f}};
#pragma unroll
        for (int ct = 0; ct < 4; ++ct)
#pragma unroll
            for (int kc = 0; kc < KC; ++kc) {
                acc[ct] = __builtin_amdgcn_mfma_f32_16x16x32_bf16(ahi[kc], whi[ct][kc], acc[ct], 0, 0, 0);
                acc[ct] = __builtin_amdgcn_mfma_f32_16x16x32_bf16(ahi[kc], wlo[ct][kc], acc[ct], 0, 0, 0);
                acc[ct] = __builtin_amdgcn_mfma_f32_16x16x32_bf16(alo[kc], whi[ct][kc], acc[ct], 0, 0, 0);
            }
#pragma unroll
        for (int ct = 0; ct < 4; ++ct)
#pragma unroll
            for (int r = 0; r < 4; ++r) {
                int row = r0 + l4 * 4 + r;
                float o = acc[ct][r] + bias[ct];
                if (RELU) o = fmaxf(o, 0.f);
                if (SCALE) o *= dinv[row];
                out[(size_t)row * 64 + ct * 16 + l15] = __float2half(o);
            }
    }
}

// ---------------- decode: out[p] = dot(enc[a], enc[b]); 8 lanes/pair, fp16 rows ----------------

__device__ __forceinline__ float dot8h(uint4 ua, uint4 ub) {
    const __half2* pa = (const __half2*)&ua;
    const __half2* pb = (const __half2*)&ub;
    float s = 0.f;
#pragma unroll
    for (int i = 0; i < 4; ++i) {
        float2 fa = __half22float2(pa[i]);
        float2 fb = __half22float2(pb[i]);
        s += fa.x * fb.x + fa.y * fb.y;
    }
    return s;
}

__global__ void __launch_bounds__(256) k_decode(
        const int* __restrict__ eli, const __half* __restrict__ enc,
        float* __restrict__ out) {
    int gid = blockIdx.x * 256 + threadIdx.x;  // EL*8 threads
    int p = gid >> 3;
    int c8 = gid & 7;  // 8 halves (16 B) per lane
    int a = eli[p];
    int b = eli[N_LABEL + p];
    uint4 ua = *(const uint4*)(enc + (size_t)a * 64 + c8 * 8);
    uint4 ub = *(const uint4*)(enc + (size_t)b * 64 + c8 * 8);
    float s = dot8h(ua, ub);
    s += __shfl_xor(s, 1, 8);
    s += __shfl_xor(s, 2, 8);
    s += __shfl_xor(s, 4, 8);
    if (c8 == 0) out[p] = s;
}

// ---------------- host ----------------

extern "C" void kernel_launch(void* const* d_in, const int* in_sizes, int n_in,
                              void* d_out, int out_size, void* d_ws, size_t ws_size,
                              hipStream_t stream) {
    const float* x   = (const float*)d_in[0];
    const int*   ei  = (const int*)d_in[1];
    const float* ew  = (const float*)d_in[2];
    const int*   eli = (const int*)d_in[3];
    const float* W[6] = {(const float*)d_in[4],  (const float*)d_in[6],
                         (const float*)d_in[8],  (const float*)d_in[10],
                         (const float*)d_in[12], (const float*)d_in[14]};
    const float* B[6] = {(const float*)d_in[5],  (const float*)d_in[7],
                         (const float*)d_in[9],  (const float*)d_in[11],
                         (const float*)d_in[13], (const float*)d_in[15]};

    char* ws = (char*)d_ws;
    unsigned long long* packed = (unsigned long long*)ws;  ws += (size_t)N_NODES * 8;
    float*          dinv    = (float*)ws;           ws += N_NODES * 4;
    int*            offs    = (int*)ws;             ws += (N_NODES + 16) * 4;
    int*            blksum  = (int*)ws;             ws += 256 * 4;
    unsigned short* rank    = (unsigned short*)ws;  ws += (size_t)N_EDGES * 2;
    int2*           csr_se  = (int2*)ws;            ws += (size_t)N_EDGES * 8;
    __half*         xh      = (__half*)ws;          ws += (size_t)N_NODES * DIM_IN * 2;
    float*          aggF    = (float*)ws;           ws += (size_t)N_NODES * 64 * 4;
    __half*         hA      = (__half*)ws;          ws += (size_t)N_NODES * 64 * 2;
    __half*         hB      = (__half*)ws;

    const int BS = 256;
    const int gAgg = N_NODES / 4;   // one 64-lane wave per node, 4 per block
    const int gGemm = 512;          // 2048 waves, 2 row-tiles each

    // CSR build + norm (one atomic per edge, rank-based gather-free fill)
    k_init <<<N_NODES / BS, BS, 0, stream>>>(packed);
    k_cnt  <<<N_EDGES / BS, BS, 0, stream>>>(ei, ew, packed, rank);
    k_scan1<<<64, BS, 0, stream>>>((const int2*)packed, blksum);
    k_scan2<<<1, 64, 0, stream>>>(blksum);
    k_scan3<<<64, BS, 0, stream>>>((const int2*)packed, blksum, offs, dinv);
    k_fill <<<N_EDGES / BS, BS, 0, stream>>>(ei, ew, offs, rank, csr_se);

    // cast x to pre-scaled fp16 (h'_0 = dinv * x)
    k_cast_x<<<N_NODES * DIM_IN / BS, BS, 0, stream>>>(x, dinv, xh);

    // layer 1 (K=32)
    k_agg<DIM_IN><<<gAgg, BS, 0, stream>>>(offs, csr_se, xh, dinv, aggF);
    k_gemm_mfma<DIM_IN, true, true><<<gGemm, BS, 0, stream>>>(aggF, W[0], B[0], dinv, hA);

    // layers 2..5 (K=64)
    k_agg<DIM_H><<<gAgg, BS, 0, stream>>>(offs, csr_se, hA, dinv, aggF);
    k_gemm_mfma<DIM_H, true, true><<<gGemm, BS, 0, stream>>>(aggF, W[1], B[1], dinv, hB);
    k_agg<DIM_H><<<gAgg, BS, 0, stream>>>(offs, csr_se, hB, dinv, aggF);
    k_gemm_mfma<DIM_H, true, true><<<gGemm, BS, 0, stream>>>(aggF, W[2], B[2], dinv, hA);
    k_agg<DIM_H><<<gAgg, BS, 0, stream>>>(offs, csr_se, hA, dinv, aggF);
    k_gemm_mfma<DIM_H, true, true><<<gGemm, BS, 0, stream>>>(aggF, W[3], B[3], dinv, hB);
    k_agg<DIM_H><<<gAgg, BS, 0, stream>>>(offs, csr_se, hB, dinv, aggF);
    k_gemm_mfma<DIM_H, true, true><<<gGemm, BS, 0, stream>>>(aggF, W[4], B[4], dinv, hA);

    // layer 6 (no relu, no scale) -> enc
    k_agg<DIM_H><<<gAgg, BS, 0, stream>>>(offs, csr_se, hA, dinv, aggF);
    k_gemm_mfma<DIM_H, false, false><<<gGemm, BS, 0, stream>>>(aggF, W[5], B[5], dinv, hB);

    // decode (8 lanes per pair)
    k_decode<<<N_LABEL * 8 / BS, BS, 0, stream>>>(eli, hB, (float*)d_out);
}